// Round 9
// baseline (1269.701 us; speedup 1.0000x reference)
//
#include <hip/hip_runtime.h>

// MixHopConv, 8 GCN props on [N,2] fp32.
// R21: layers declared at HW random-line ceiling (6 neutral experiments;
// 0.27 lines/cyc/CU from L2/L3, insensitive to MLP/occupancy/LDS levers).
// Attack preprocessing instead: within-bucket order is irrelevant (R15), so
// fuse the two-phase sort into ONE pass with PLAIN (unswizzled) col2 layout.
// R17's 305MB write blowup was the swizzle scattering each 4B store to its
// own line; with plain layout each (chunk,bucket) run writes CONTIGUOUSLY
// (~1.5x line amplification). Pipeline:
//   k_fill : col2=SENT + zero deg/gbase            (~8us)
//   k_sort : lsort's LDS counting sort by dst-bucket + global deg atomics +
//            per-(block,bucket) atomicAdd(gbase) + contiguous run writeback
//   k_qtab : deg -> dis + folded layer-0 gather table (~4us)
//   layers : R20 gather_acc unchanged; ebuf reads plain layout
//            (thread t owns slots [20t,20t+20) = 5 aligned dwordx4)
// col entry: (local_dst<<19)|src; local_dst 0..511; 512=sentinel.

constexpr int NN = 500000;
constexpr int NE = 8000000;
constexpr int STEP_DIM = 8;
constexpr int HIDM1 = 7;

constexpr int BSH  = 9;
constexpr int BNOD = 1 << BSH;                  // 512 nodes / bucket
constexpr int NBUK = (NN + BNOD - 1) / BNOD;    // 977
constexpr int SLOT = 10240;                     // 20 slots/thread * 512 (mean 8190, +22 sigma)
constexpr unsigned SENT = (unsigned)BNOD << 19; // sentinel -> dump row

constexpr int PA_NBLK = 500;
constexpr int PA_EPB  = NE / PA_NBLK;           // 16000 edges / chunk
constexpr int PA_QPB  = PA_EPB / 4;

constexpr int DEG_PAD = 500224;                 // padded N (mult of 4)
constexpr int GB_PAD  = 1024;                   // gbase pad

typedef unsigned u32x4 __attribute__((ext_vector_type(4)));
typedef float    f32x2 __attribute__((ext_vector_type(2)));

// ---- phase 0: init col2 to SENT, zero deg + gbase --------------------------

__global__ __launch_bounds__(256) void k_fill(unsigned* __restrict__ col2,
                                              int* __restrict__ degz) {
  int idx = blockIdx.x * 256 + threadIdx.x;
  int stride = gridDim.x * 256;
  const int NC4 = (NBUK * SLOT) / 4;            // 2,501,120
  u32x4 sv;
  sv[0] = SENT; sv[1] = SENT; sv[2] = SENT; sv[3] = SENT;
  u32x4* c4 = (u32x4*)col2;
  for (int i = idx; i < NC4; i += stride) c4[i] = sv;
  const int ND4 = (DEG_PAD + GB_PAD) / 4;
  int4 z = make_int4(0, 0, 0, 0);
  int4* d4 = (int4*)degz;
  for (int i = idx; i < ND4; i += stride) d4[i] = z;
}

// ---- phase 1: fused per-chunk counting sort + contiguous run writeback -----

__global__ __launch_bounds__(512) void k_sort(const int* __restrict__ src,
                                              const int* __restrict__ dst,
                                              unsigned* __restrict__ col2,
                                              int* __restrict__ deg,
                                              int* __restrict__ gbase) {
  __shared__ unsigned stage[PA_EPB];   // 62.5 KB
  __shared__ int hist[NBUK];           // 3.9 KB (starts, bumped to ends)
  __shared__ int st2[NBUK];            // 3.9 KB (stable starts)
  __shared__ int tsum[512];            // 2 KB
  int b = blockIdx.x, t = threadIdx.x;
  for (int h = t; h < NBUK; h += 512) hist[h] = 0;
  __syncthreads();
  const int4* d4p = (const int4*)dst + (size_t)b * PA_QPB;
  const int4* s4p = (const int4*)src + (size_t)b * PA_QPB;
  // count pass + global degree atomics
  for (int i = t; i < PA_QPB; i += 512) {
    int4 d = d4p[i];
    atomicAdd(&hist[d.x >> BSH], 1);
    atomicAdd(&hist[d.y >> BSH], 1);
    atomicAdd(&hist[d.z >> BSH], 1);
    atomicAdd(&hist[d.w >> BSH], 1);
    atomicAdd(&deg[d.x], 1);
    atomicAdd(&deg[d.y], 1);
    atomicAdd(&deg[d.z], 1);
    atomicAdd(&deg[d.w], 1);
  }
  __syncthreads();
  // block scan over 977 bins (2 bins/thread)
  int h0 = 2 * t, h1 = 2 * t + 1;
  int a0 = (h0 < NBUK) ? hist[h0] : 0;
  int a1 = (h1 < NBUK) ? hist[h1] : 0;
  tsum[t] = a0 + a1;
  __syncthreads();
  for (int o = 1; o < 512; o <<= 1) {
    int v = (t >= o) ? tsum[t - o] : 0;
    __syncthreads();
    tsum[t] += v;
    __syncthreads();
  }
  int ex = tsum[t] - (a0 + a1);
  __syncthreads();
  if (h0 < NBUK) { hist[h0] = ex;      st2[h0] = ex; }
  if (h1 < NBUK) { hist[h1] = ex + a0; st2[h1] = ex + a0; }
  __syncthreads();
  // placement pass (LDS scatter into bucket-grouped stage)
  for (int i = t; i < PA_QPB; i += 512) {
    int4 d = d4p[i];
    int4 s = s4p[i];
    int p0 = atomicAdd(&hist[d.x >> BSH], 1);
    stage[p0] = ((unsigned)(d.x & (BNOD - 1)) << 19) | (unsigned)s.x;
    int p1 = atomicAdd(&hist[d.y >> BSH], 1);
    stage[p1] = ((unsigned)(d.y & (BNOD - 1)) << 19) | (unsigned)s.y;
    int p2 = atomicAdd(&hist[d.z >> BSH], 1);
    stage[p2] = ((unsigned)(d.z & (BNOD - 1)) << 19) | (unsigned)s.z;
    int p3 = atomicAdd(&hist[d.w >> BSH], 1);
    stage[p3] = ((unsigned)(d.w & (BNOD - 1)) << 19) | (unsigned)s.w;
  }
  __syncthreads();
  // reserve + CONTIGUOUS writeback: one 16-lane group per bucket-run.
  // hist[bin] is now END of bin's run; st2[bin] its start. Run ~16 edges ->
  // 1-2 lines, written dense (no swizzle -> no line scatter).
  int g16 = t >> 4, gl = t & 15;       // 32 groups
  int lane = t & 63;
  for (int bin = g16; bin < NBUK; bin += 32) {
    int st = st2[bin];
    int cnt = hist[bin] - st;
    int base = 0;
    if (gl == 0 && cnt > 0) base = atomicAdd(&gbase[bin], cnt);
    base = __shfl(base, lane & ~15, 64);
    unsigned* outp = col2 + (size_t)bin * SLOT;
    for (int k = gl; k < cnt; k += 16) {
      int p = base + k;
      if (p < SLOT) outp[p] = stage[st + k];
    }
  }
}

// ---- phase 2: node init (dis + folded layer-0 gather table) ----------------

__global__ __launch_bounds__(512) void k_qtab(const int* __restrict__ deg,
                                              const float2* __restrict__ X,
                                              const float* __restrict__ W0,
                                              const float* __restrict__ step_emb,
                                              const int* __restrict__ step_index,
                                              float* __restrict__ dis,
                                              float2* __restrict__ qtab) {
  int i = blockIdx.x * 512 + threadIdx.x;
  if (i >= NN) return;
  float d = rsqrtf((float)deg[i] + 1.0f);
  dis[i] = d;
  float2 x = X[i];
  const float* sv = step_emb + step_index[0] * STEP_DIM;
  float c1_0 = 0.f, c1_1 = 0.f;
#pragma unroll
  for (int j = 0; j < STEP_DIM; ++j) {
    c1_0 += sv[j] * W0[20 + (2 + j) * 2 + 0];
    c1_1 += sv[j] * W0[20 + (2 + j) * 2 + 1];
  }
  qtab[i] = make_float2(d * (x.x * W0[20] + x.y * W0[22] + c1_0),
                        d * (x.x * W0[21] + x.y * W0[23] + c1_1));
}

// ---- shared layer helpers --------------------------------------------------

// plain layout: thread t owns slots [20t, 20t+20) = 80B = 5 aligned dwordx4.
__device__ __forceinline__ void load_ebuf(const unsigned* __restrict__ col2,
                                          int b, int t, unsigned* ebuf) {
  const unsigned* bp = col2 + (size_t)b * SLOT + t * 20;
#pragma unroll
  for (int g = 0; g < 5; ++g) {
    u32x4 v = *(const u32x4*)(bp + g * 4);
    ebuf[g * 4 + 0] = v[0];
    ebuf[g * 4 + 1] = v[1];
    ebuf[g * 4 + 2] = v[2];
    ebuf[g * 4 + 3] = v[3];
  }
}

// R20 gather_acc unchanged (verified): 20 gathers issued upfront + fence,
// then order-agnostic run-scan into LDS acc.
__device__ __forceinline__ void gather_acc(const unsigned* ebuf,
                                           const float2* __restrict__ tab,
                                           float* acc) {
  const f32x2* tv = (const f32x2*)tab;
  f32x2 vals[20];
#pragma unroll
  for (int j = 0; j < 20; ++j) vals[j] = tv[ebuf[j] & 0x7FFFF];
  asm volatile("" ::: "memory");  // loads cannot sink past this point
  int cur = BNOD;
  float rx = 0.f, ry = 0.f;
#pragma unroll
  for (int j = 0; j < 20; ++j) {
    int ld = (int)(ebuf[j] >> 19);
    if (ld != cur) {
      atomicAdd(&acc[cur * 2 + 0], rx);
      atomicAdd(&acc[cur * 2 + 1], ry);
      cur = ld;
      rx = vals[j][0];
      ry = vals[j][1];
    } else {
      rx += vals[j][0];
      ry += vals[j][1];
    }
  }
  atomicAdd(&acc[cur * 2 + 0], rx);
  atomicAdd(&acc[cur * 2 + 1], ry);
}

// ---- layer kernels ---------------------------------------------------------

__global__ __launch_bounds__(512, 4) void k_blayer0(const unsigned* __restrict__ col2,
                                                    const float2* __restrict__ qtab,
                                                    const float2* __restrict__ X,
                                                    const float* __restrict__ dis,
                                                    const float* __restrict__ W0,
                                                    const float* __restrict__ b0,
                                                    const float* __restrict__ step_emb,
                                                    const int* __restrict__ step_index,
                                                    float2* __restrict__ xs_out) {
  __shared__ float acc[(BNOD + 1) * 2];
  int b = blockIdx.x, t = threadIdx.x;
  for (int j = t; j < (BNOD + 1) * 2; j += 512) acc[j] = 0.f;
  __syncthreads();
  unsigned ebuf[20];
  load_ebuf(col2, b, t, ebuf);
  gather_acc(ebuf, qtab, acc);
  __syncthreads();
  const float* sv = step_emb + step_index[0] * STEP_DIM;
  float c00 = b0[0] + b0[2], c01 = b0[1] + b0[3];
#pragma unroll
  for (int j = 0; j < STEP_DIM; ++j) {
    c00 += sv[j] * W0[(2 + j) * 2 + 0];
    c01 += sv[j] * W0[(2 + j) * 2 + 1];
  }
  int i = (b << BSH) + t;
  if (i < NN) {
    float d = dis[i];
    float2 x = X[i];
    float2 qv = qtab[i];
    float h0 = c00 + x.x * W0[0] + x.y * W0[2] + d * (acc[t * 2 + 0] + qv.x);
    float h1 = c01 + x.x * W0[1] + x.y * W0[3] + d * (acc[t * 2 + 1] + qv.y);
    h0 = fmaxf(h0, 0.f);
    h1 = fmaxf(h1, 0.f);
    xs_out[i] = make_float2(d * h0, d * h1);
  }
}

__global__ __launch_bounds__(512, 4) void k_blayer(const unsigned* __restrict__ col2,
                                                   const float* __restrict__ dis,
                                                   const float2* __restrict__ xs_in,
                                                   const float* __restrict__ W,
                                                   const float* __restrict__ bb,
                                                   float2* __restrict__ xs_out,
                                                   float2* __restrict__ out,
                                                   int last) {
  __shared__ float acc[(BNOD + 1) * 2];
  int b = blockIdx.x, t = threadIdx.x;
  for (int j = t; j < (BNOD + 1) * 2; j += 512) acc[j] = 0.f;
  __syncthreads();
  unsigned ebuf[20];
  load_ebuf(col2, b, t, ebuf);
  gather_acc(ebuf, xs_in, acc);
  __syncthreads();
  int i = (b << BSH) + t;
  if (i < NN) {
    float d = dis[i];
    float2 xsv = xs_in[i];
    float inv = 1.0f / d;
    float xx = xsv.x * inv, xy = xsv.y * inv;
    float px = d * (acc[t * 2 + 0] + xsv.x);
    float py = d * (acc[t * 2 + 1] + xsv.y);
    float h0 = bb[0] + bb[2] + xx * W[0] + xy * W[2] + px * W[4] + py * W[6];
    float h1 = bb[1] + bb[3] + xx * W[1] + xy * W[3] + px * W[5] + py * W[7];
    h0 = fmaxf(h0, 0.f);
    h1 = fmaxf(h1, 0.f);
    if (last) {
      out[i] = make_float2(h0, h1);
    } else {
      xs_out[i] = make_float2(d * h0, d * h1);
    }
  }
}

// ---- driver ----------------------------------------------------------------

extern "C" void kernel_launch(void* const* d_in, const int* in_sizes, int n_in,
                              void* d_out, int out_size, void* d_ws, size_t ws_size,
                              hipStream_t stream) {
  const float2* X        = (const float2*)d_in[0];
  const int*    edge     = (const int*)d_in[1];
  const int*    src      = edge;
  const int*    dstp     = edge + NE;
  const int*    step_idx = (const int*)d_in[2];
  const float*  step_emb = (const float*)d_in[3];
  const float*  W0       = (const float*)d_in[4];
  const float*  b0       = (const float*)d_in[5];
  const float*  Wh       = (const float*)d_in[6];
  const float*  bbias    = (const float*)d_in[7];

  // ws ints: [col2: 977*10240][deg: 500224][gbase: 1024][dis: 500224]
  //          [bufA: 1000448][bufB: 1000448]
  int*      ip    = (int*)d_ws;
  unsigned* col2  = (unsigned*)ip;
  int*      deg   = ip + (size_t)NBUK * SLOT;
  int*      gbase = deg + DEG_PAD;
  float*    dis   = (float*)(gbase + GB_PAD);
  float2*   bufA  = (float2*)(dis + DEG_PAD);
  float2*   bufB  = bufA + DEG_PAD;

  k_fill<<<2048, 256, 0, stream>>>(col2, deg);
  k_sort<<<PA_NBLK, 512, 0, stream>>>(src, dstp, col2, deg, gbase);
  k_qtab<<<NBUK, 512, 0, stream>>>(deg, X, W0, step_emb, step_idx, dis, bufA);

  k_blayer0<<<NBUK, 512, 0, stream>>>(col2, bufA, X, dis, W0, b0,
                                      step_emb, step_idx, bufB);
  float2* cur = bufB;
  float2* nxt = bufA;
  for (int l = 0; l < HIDM1; ++l) {
    k_blayer<<<NBUK, 512, 0, stream>>>(col2, dis, cur, Wh + l * 8,
                                       bbias + l * 4, nxt, (float2*)d_out,
                                       l == HIDM1 - 1 ? 1 : 0);
    float2* tmp = cur;
    cur = nxt;
    nxt = tmp;
  }
}

// Round 10
// 1030.677 us; speedup vs baseline: 1.2319x; 1.2319x over previous
//
#include <hip/hip_runtime.h>

// MixHopConv, 8 GCN props on [N,2] fp32.
// R22: R21's 292MB WRITE was NOT layout (plain == swizzled == ~300MB). Common
// factor vs two-phase (63MB): 8M global deg atomicAdds -> memory-side EA
// write transactions (8M x 32B = 256MB) + col2 36MB = 292MB, and dur = that
// traffic / ~900GB/s. Fix: drop per-edge deg atomics; recover degrees AFTER
// the sort by histogramming col2's embedded local_dst (k_deg, one block per
// bucket, coalesced stream + LDS hist — what sortA used to do), folding in
// the dis/qtab node-init. Pipeline:
//   k_fill : col2=SENT + zero gbase                (~8us)
//   k_sort : LDS counting sort by dst-bucket + per-(block,bucket)
//            atomicAdd(gbase) reservation + contiguous run writeback
//   k_deg  : per-bucket local_dst histogram -> dis + qtab  (~15us)
//   layers : unchanged (plain layout, R21-verified)
// col entry: (local_dst<<19)|src; local_dst 0..511; 512=sentinel.

constexpr int NN = 500000;
constexpr int NE = 8000000;
constexpr int STEP_DIM = 8;
constexpr int HIDM1 = 7;

constexpr int BSH  = 9;
constexpr int BNOD = 1 << BSH;                  // 512 nodes / bucket
constexpr int NBUK = (NN + BNOD - 1) / BNOD;    // 977
constexpr int SLOT = 10240;                     // 20 slots/thread * 512 (mean 8190, +22 sigma)
constexpr unsigned SENT = (unsigned)BNOD << 19; // sentinel -> dump row

constexpr int PA_NBLK = 500;
constexpr int PA_EPB  = NE / PA_NBLK;           // 16000 edges / chunk
constexpr int PA_QPB  = PA_EPB / 4;

constexpr int DEG_PAD = 500224;                 // padded N (mult of 4)
constexpr int GB_PAD  = 1024;                   // gbase pad

typedef unsigned u32x4 __attribute__((ext_vector_type(4)));
typedef float    f32x2 __attribute__((ext_vector_type(2)));

// ---- phase 0: init col2 to SENT, zero gbase --------------------------------

__global__ __launch_bounds__(256) void k_fill(unsigned* __restrict__ col2,
                                              int* __restrict__ gbase) {
  int idx = blockIdx.x * 256 + threadIdx.x;
  int stride = gridDim.x * 256;
  const int NC4 = (NBUK * SLOT) / 4;            // 2,501,120
  u32x4 sv;
  sv[0] = SENT; sv[1] = SENT; sv[2] = SENT; sv[3] = SENT;
  u32x4* c4 = (u32x4*)col2;
  for (int i = idx; i < NC4; i += stride) c4[i] = sv;
  if (idx < GB_PAD) gbase[idx] = 0;
}

// ---- phase 1: fused per-chunk counting sort + contiguous run writeback -----

__global__ __launch_bounds__(512) void k_sort(const int* __restrict__ src,
                                              const int* __restrict__ dst,
                                              unsigned* __restrict__ col2,
                                              int* __restrict__ gbase) {
  __shared__ unsigned stage[PA_EPB];   // 62.5 KB
  __shared__ int hist[NBUK];           // 3.9 KB (starts, bumped to ends)
  __shared__ int st2[NBUK];            // 3.9 KB (stable starts)
  __shared__ int tsum[512];            // 2 KB
  int b = blockIdx.x, t = threadIdx.x;
  for (int h = t; h < NBUK; h += 512) hist[h] = 0;
  __syncthreads();
  const int4* d4p = (const int4*)dst + (size_t)b * PA_QPB;
  const int4* s4p = (const int4*)src + (size_t)b * PA_QPB;
  // count pass (LDS only — NO global atomics)
  for (int i = t; i < PA_QPB; i += 512) {
    int4 d = d4p[i];
    atomicAdd(&hist[d.x >> BSH], 1);
    atomicAdd(&hist[d.y >> BSH], 1);
    atomicAdd(&hist[d.z >> BSH], 1);
    atomicAdd(&hist[d.w >> BSH], 1);
  }
  __syncthreads();
  // block scan over 977 bins (2 bins/thread)
  int h0 = 2 * t, h1 = 2 * t + 1;
  int a0 = (h0 < NBUK) ? hist[h0] : 0;
  int a1 = (h1 < NBUK) ? hist[h1] : 0;
  tsum[t] = a0 + a1;
  __syncthreads();
  for (int o = 1; o < 512; o <<= 1) {
    int v = (t >= o) ? tsum[t - o] : 0;
    __syncthreads();
    tsum[t] += v;
    __syncthreads();
  }
  int ex = tsum[t] - (a0 + a1);
  __syncthreads();
  if (h0 < NBUK) { hist[h0] = ex;      st2[h0] = ex; }
  if (h1 < NBUK) { hist[h1] = ex + a0; st2[h1] = ex + a0; }
  __syncthreads();
  // placement pass (LDS scatter into bucket-grouped stage)
  for (int i = t; i < PA_QPB; i += 512) {
    int4 d = d4p[i];
    int4 s = s4p[i];
    int p0 = atomicAdd(&hist[d.x >> BSH], 1);
    stage[p0] = ((unsigned)(d.x & (BNOD - 1)) << 19) | (unsigned)s.x;
    int p1 = atomicAdd(&hist[d.y >> BSH], 1);
    stage[p1] = ((unsigned)(d.y & (BNOD - 1)) << 19) | (unsigned)s.y;
    int p2 = atomicAdd(&hist[d.z >> BSH], 1);
    stage[p2] = ((unsigned)(d.z & (BNOD - 1)) << 19) | (unsigned)s.z;
    int p3 = atomicAdd(&hist[d.w >> BSH], 1);
    stage[p3] = ((unsigned)(d.w & (BNOD - 1)) << 19) | (unsigned)s.w;
  }
  __syncthreads();
  // reserve + CONTIGUOUS writeback: one 16-lane group per bucket-run.
  int g16 = t >> 4, gl = t & 15;       // 32 groups
  int lane = t & 63;
  for (int bin = g16; bin < NBUK; bin += 32) {
    int st = st2[bin];
    int cnt = hist[bin] - st;
    int base = 0;
    if (gl == 0 && cnt > 0) base = atomicAdd(&gbase[bin], cnt);
    base = __shfl(base, lane & ~15, 64);
    unsigned* outp = col2 + (size_t)bin * SLOT;
    for (int k = gl; k < cnt; k += 16) {
      int p = base + k;
      if (p < SLOT) outp[p] = stage[st + k];
    }
  }
}

// ---- phase 2: per-bucket degree histogram + node init ----------------------

__global__ __launch_bounds__(512) void k_deg(const unsigned* __restrict__ col2,
                                             const int* __restrict__ gbase,
                                             const float2* __restrict__ X,
                                             const float* __restrict__ W0,
                                             const float* __restrict__ step_emb,
                                             const int* __restrict__ step_index,
                                             float* __restrict__ dis,
                                             float2* __restrict__ qtab) {
  __shared__ int hist[BNOD];
  int h = blockIdx.x, t = threadIdx.x;
  hist[t] = 0;
  __syncthreads();
  int cnt = gbase[h];
  if (cnt > SLOT) cnt = SLOT;
  const unsigned* base = col2 + (size_t)h * SLOT;
  for (int i = t; i < cnt; i += 512)
    atomicAdd(&hist[base[i] >> 19], 1);
  __syncthreads();
  int deg = hist[t];
  int i = (h << BSH) + t;
  if (i < NN) {
    float d = rsqrtf((float)deg + 1.0f);
    dis[i] = d;
    float2 x = X[i];
    const float* sv = step_emb + step_index[0] * STEP_DIM;
    float c1_0 = 0.f, c1_1 = 0.f;
#pragma unroll
    for (int j = 0; j < STEP_DIM; ++j) {
      c1_0 += sv[j] * W0[20 + (2 + j) * 2 + 0];
      c1_1 += sv[j] * W0[20 + (2 + j) * 2 + 1];
    }
    qtab[i] = make_float2(d * (x.x * W0[20] + x.y * W0[22] + c1_0),
                          d * (x.x * W0[21] + x.y * W0[23] + c1_1));
  }
}

// ---- shared layer helpers --------------------------------------------------

// plain layout: thread t owns slots [20t, 20t+20) = 80B = 5 aligned dwordx4.
__device__ __forceinline__ void load_ebuf(const unsigned* __restrict__ col2,
                                          int b, int t, unsigned* ebuf) {
  const unsigned* bp = col2 + (size_t)b * SLOT + t * 20;
#pragma unroll
  for (int g = 0; g < 5; ++g) {
    u32x4 v = *(const u32x4*)(bp + g * 4);
    ebuf[g * 4 + 0] = v[0];
    ebuf[g * 4 + 1] = v[1];
    ebuf[g * 4 + 2] = v[2];
    ebuf[g * 4 + 3] = v[3];
  }
}

// 20 gathers issued upfront + fence, then order-agnostic run-scan into LDS.
__device__ __forceinline__ void gather_acc(const unsigned* ebuf,
                                           const float2* __restrict__ tab,
                                           float* acc) {
  const f32x2* tv = (const f32x2*)tab;
  f32x2 vals[20];
#pragma unroll
  for (int j = 0; j < 20; ++j) vals[j] = tv[ebuf[j] & 0x7FFFF];
  asm volatile("" ::: "memory");  // loads cannot sink past this point
  int cur = BNOD;
  float rx = 0.f, ry = 0.f;
#pragma unroll
  for (int j = 0; j < 20; ++j) {
    int ld = (int)(ebuf[j] >> 19);
    if (ld != cur) {
      atomicAdd(&acc[cur * 2 + 0], rx);
      atomicAdd(&acc[cur * 2 + 1], ry);
      cur = ld;
      rx = vals[j][0];
      ry = vals[j][1];
    } else {
      rx += vals[j][0];
      ry += vals[j][1];
    }
  }
  atomicAdd(&acc[cur * 2 + 0], rx);
  atomicAdd(&acc[cur * 2 + 1], ry);
}

// ---- layer kernels ---------------------------------------------------------

__global__ __launch_bounds__(512, 4) void k_blayer0(const unsigned* __restrict__ col2,
                                                    const float2* __restrict__ qtab,
                                                    const float2* __restrict__ X,
                                                    const float* __restrict__ dis,
                                                    const float* __restrict__ W0,
                                                    const float* __restrict__ b0,
                                                    const float* __restrict__ step_emb,
                                                    const int* __restrict__ step_index,
                                                    float2* __restrict__ xs_out) {
  __shared__ float acc[(BNOD + 1) * 2];
  int b = blockIdx.x, t = threadIdx.x;
  for (int j = t; j < (BNOD + 1) * 2; j += 512) acc[j] = 0.f;
  __syncthreads();
  unsigned ebuf[20];
  load_ebuf(col2, b, t, ebuf);
  gather_acc(ebuf, qtab, acc);
  __syncthreads();
  const float* sv = step_emb + step_index[0] * STEP_DIM;
  float c00 = b0[0] + b0[2], c01 = b0[1] + b0[3];
#pragma unroll
  for (int j = 0; j < STEP_DIM; ++j) {
    c00 += sv[j] * W0[(2 + j) * 2 + 0];
    c01 += sv[j] * W0[(2 + j) * 2 + 1];
  }
  int i = (b << BSH) + t;
  if (i < NN) {
    float d = dis[i];
    float2 x = X[i];
    float2 qv = qtab[i];
    float h0 = c00 + x.x * W0[0] + x.y * W0[2] + d * (acc[t * 2 + 0] + qv.x);
    float h1 = c01 + x.x * W0[1] + x.y * W0[3] + d * (acc[t * 2 + 1] + qv.y);
    h0 = fmaxf(h0, 0.f);
    h1 = fmaxf(h1, 0.f);
    xs_out[i] = make_float2(d * h0, d * h1);
  }
}

__global__ __launch_bounds__(512, 4) void k_blayer(const unsigned* __restrict__ col2,
                                                   const float* __restrict__ dis,
                                                   const float2* __restrict__ xs_in,
                                                   const float* __restrict__ W,
                                                   const float* __restrict__ bb,
                                                   float2* __restrict__ xs_out,
                                                   float2* __restrict__ out,
                                                   int last) {
  __shared__ float acc[(BNOD + 1) * 2];
  int b = blockIdx.x, t = threadIdx.x;
  for (int j = t; j < (BNOD + 1) * 2; j += 512) acc[j] = 0.f;
  __syncthreads();
  unsigned ebuf[20];
  load_ebuf(col2, b, t, ebuf);
  gather_acc(ebuf, xs_in, acc);
  __syncthreads();
  int i = (b << BSH) + t;
  if (i < NN) {
    float d = dis[i];
    float2 xsv = xs_in[i];
    float inv = 1.0f / d;
    float xx = xsv.x * inv, xy = xsv.y * inv;
    float px = d * (acc[t * 2 + 0] + xsv.x);
    float py = d * (acc[t * 2 + 1] + xsv.y);
    float h0 = bb[0] + bb[2] + xx * W[0] + xy * W[2] + px * W[4] + py * W[6];
    float h1 = bb[1] + bb[3] + xx * W[1] + xy * W[3] + px * W[5] + py * W[7];
    h0 = fmaxf(h0, 0.f);
    h1 = fmaxf(h1, 0.f);
    if (last) {
      out[i] = make_float2(h0, h1);
    } else {
      xs_out[i] = make_float2(d * h0, d * h1);
    }
  }
}

// ---- driver ----------------------------------------------------------------

extern "C" void kernel_launch(void* const* d_in, const int* in_sizes, int n_in,
                              void* d_out, int out_size, void* d_ws, size_t ws_size,
                              hipStream_t stream) {
  const float2* X        = (const float2*)d_in[0];
  const int*    edge     = (const int*)d_in[1];
  const int*    src      = edge;
  const int*    dstp     = edge + NE;
  const int*    step_idx = (const int*)d_in[2];
  const float*  step_emb = (const float*)d_in[3];
  const float*  W0       = (const float*)d_in[4];
  const float*  b0       = (const float*)d_in[5];
  const float*  Wh       = (const float*)d_in[6];
  const float*  bbias    = (const float*)d_in[7];

  // ws ints: [col2: 977*10240][gbase: 1024][dis: 500224]
  //          [bufA: 1000448][bufB: 1000448]
  int*      ip    = (int*)d_ws;
  unsigned* col2  = (unsigned*)ip;
  int*      gbase = ip + (size_t)NBUK * SLOT;
  float*    dis   = (float*)(gbase + GB_PAD);
  float2*   bufA  = (float2*)(dis + DEG_PAD);
  float2*   bufB  = bufA + DEG_PAD;

  k_fill<<<2048, 256, 0, stream>>>(col2, gbase);
  k_sort<<<PA_NBLK, 512, 0, stream>>>(src, dstp, col2, gbase);
  k_deg<<<NBUK, 512, 0, stream>>>(col2, gbase, X, W0, step_emb, step_idx,
                                  dis, bufA);

  k_blayer0<<<NBUK, 512, 0, stream>>>(col2, bufA, X, dis, W0, b0,
                                      step_emb, step_idx, bufB);
  float2* cur = bufB;
  float2* nxt = bufA;
  for (int l = 0; l < HIDM1; ++l) {
    k_blayer<<<NBUK, 512, 0, stream>>>(col2, dis, cur, Wh + l * 8,
                                       bbias + l * 4, nxt, (float2*)d_out,
                                       l == HIDM1 - 1 ? 1 : 0);
    float2* tmp = cur;
    cur = nxt;
    nxt = tmp;
  }
}

// Round 11
// 544.644 us; speedup vs baseline: 2.3313x; 1.8924x over previous
//
#include <hip/hip_runtime.h>

// MixHopConv, 8 GCN props on [N,2] fp32.
// R23: REVERT to R16 (best verified: 545.1us; R15 546.7, R20 547.1 — same
// structure within noise). Final ledger:
//  - Layers (49us x 8): at HW random-gather ceiling, 0.27 lines/cyc/CU from
//    L2/L3. Six neutral levers: LDS-flush /3.6, MLP 4->20, pinned-MLP fence,
//    col2 NT policy, launch_bounds 8->4. NT gathers bypass L2/L3 (306MB HBM,
//    2.2x slower) — gathers ARE L2/L3-served.
//  - Preprocessing (154us): two-phase LDS counting sort. Alternatives all
//    slower: fused+global-deg-atomics 1226/1270 (8M atomics = 256MB EA
//    writes); fused w/o atomics 1031 (scattered run writeback 770GB/s AND
//    layers regress 49->108us without dst-sorted swizzled layout — measured
//    twice); cooperative grid.sync fusion 1562 (~150us/sync).
//  - Swizzled dst-sorted col2 is load-bearing for the layer floor.
// col entry: (local_dst<<19)|src; local_dst 0..511; 512=sentinel.

constexpr int NN = 500000;
constexpr int NE = 8000000;
constexpr int STEP_DIM = 8;
constexpr int HIDM1 = 7;

constexpr int BSH  = 9;
constexpr int BNOD = 1 << BSH;                  // 512 nodes / bucket
constexpr int NBUK = (NN + BNOD - 1) / BNOD;    // 977
constexpr int SLOT = 10240;                     // 20 slots/thread * 512 (mean 8190, +22 sigma)
constexpr int WSLOT = 1280;                     // per-wave window (64 lanes * 20)
constexpr unsigned SENT = (unsigned)BNOD << 19; // sentinel -> dump row

constexpr int PA_NBLK = 500;
constexpr int PA_EPB  = NE / PA_NBLK;           // 16000 edges / chunk
constexpr int PA_QPB  = PA_EPB / 4;
constexpr int PA_SC   = NBUK + 1;               // starts2 stride (978)

typedef unsigned u32x4 __attribute__((ext_vector_type(4)));

// logical slot p -> physical (so thread l's 20 logical slots are read as
// 5 coalesced dwordx4: phys = w*1280 + (j>>2)*256 + l*4 + (j&3), j = p%20)
__device__ __forceinline__ int swiz(int p) {
  int w = p / WSLOT;
  int r = p - w * WSLOT;
  int tid = r / 20;
  int j = r - tid * 20;
  return w * WSLOT + ((j >> 2) << 8) + (tid << 2) + (j & 3);
}

__device__ __forceinline__ int wave_iscan(int v, int lane) {
#pragma unroll
  for (int off = 1; off < 64; off <<= 1) {
    int n = __shfl_up(v, off, 64);
    if (lane >= off) v += n;
  }
  return v;
}

// ---- phase 1: per-chunk LDS counting sort by bucket, linear stream-out -----

__global__ __launch_bounds__(512) void k_lsort(const int* __restrict__ src,
                                               const int* __restrict__ dst,
                                               unsigned* __restrict__ colraw,
                                               int* __restrict__ starts2) {
  __shared__ unsigned stage[PA_EPB];   // 62.5 KB
  __shared__ int hist[NBUK];
  __shared__ int tsum[512];
  int b = blockIdx.x, t = threadIdx.x;
  for (int h = t; h < NBUK; h += 512) hist[h] = 0;
  __syncthreads();
  const int4* d4p = (const int4*)dst + (size_t)b * PA_QPB;
  const int4* s4p = (const int4*)src + (size_t)b * PA_QPB;
  for (int i = t; i < PA_QPB; i += 512) {
    int4 d = d4p[i];
    atomicAdd(&hist[d.x >> BSH], 1);
    atomicAdd(&hist[d.y >> BSH], 1);
    atomicAdd(&hist[d.z >> BSH], 1);
    atomicAdd(&hist[d.w >> BSH], 1);
  }
  __syncthreads();
  int h0 = 2 * t, h1 = 2 * t + 1;
  int a0 = (h0 < NBUK) ? hist[h0] : 0;
  int a1 = (h1 < NBUK) ? hist[h1] : 0;
  tsum[t] = a0 + a1;
  __syncthreads();
  for (int o = 1; o < 512; o <<= 1) {
    int v = (t >= o) ? tsum[t - o] : 0;
    __syncthreads();
    tsum[t] += v;
    __syncthreads();
  }
  int ex = tsum[t] - (a0 + a1);
  __syncthreads();
  if (h0 < NBUK) hist[h0] = ex;
  if (h1 < NBUK) hist[h1] = ex + a0;
  __syncthreads();
  int* st = starts2 + (size_t)b * PA_SC;
  for (int h = t; h < NBUK; h += 512) st[h] = hist[h];
  if (t == 0) st[NBUK] = PA_EPB;
  __syncthreads();
  for (int i = t; i < PA_QPB; i += 512) {
    int4 d = d4p[i];
    int4 s = s4p[i];
    int p0 = atomicAdd(&hist[d.x >> BSH], 1);
    stage[p0] = ((unsigned)(d.x & (BNOD - 1)) << 19) | (unsigned)s.x;
    int p1 = atomicAdd(&hist[d.y >> BSH], 1);
    stage[p1] = ((unsigned)(d.y & (BNOD - 1)) << 19) | (unsigned)s.y;
    int p2 = atomicAdd(&hist[d.z >> BSH], 1);
    stage[p2] = ((unsigned)(d.z & (BNOD - 1)) << 19) | (unsigned)s.z;
    int p3 = atomicAdd(&hist[d.w >> BSH], 1);
    stage[p3] = ((unsigned)(d.w & (BNOD - 1)) << 19) | (unsigned)s.w;
  }
  __syncthreads();
  u32x4* out4 = (u32x4*)(colraw + (size_t)b * PA_EPB);
  for (int i = t; i < PA_QPB; i += 512) {
    u32x4 q;
    q[0] = stage[4 * i + 0];
    q[1] = stage[4 * i + 1];
    q[2] = stage[4 * i + 2];
    q[3] = stage[4 * i + 3];
    __builtin_nontemporal_store(q, out4 + i);
  }
}

// ---- phase 2: cooperative run copy + dst sort + swizzle --------------------
// Also emits dis[i] and the folded layer-0 gather table qtab.

__global__ __launch_bounds__(512) void k_sortA(const unsigned* __restrict__ colraw,
                                               const int* __restrict__ starts2,
                                               unsigned* __restrict__ col2,
                                               const float2* __restrict__ X,
                                               const float* __restrict__ W0,
                                               const float* __restrict__ step_emb,
                                               const int* __restrict__ step_index,
                                               float* __restrict__ dis,
                                               float2* __restrict__ qtab) {
  __shared__ unsigned stage[SLOT];     // 40 KB
  __shared__ int hist[BNOD];           // 2 KB (512 dst bins)
  __shared__ int rp[PA_NBLK + 1];      // run start positions (2 KB)
  __shared__ int rs[PA_NBLK];          // run source offsets (2 KB)
  __shared__ int wpart[8];
  int h = blockIdx.x, t = threadIdx.x;
  int wv = t >> 6, lane = t & 63;
  // run table from starts2 (one run per chunk)
  int s = 0, len = 0;
  if (t < PA_NBLK) {
    s = starts2[(size_t)t * PA_SC + h];
    len = starts2[(size_t)t * PA_SC + h + 1] - s;
  }
  hist[t] = 0;
  // wave scan of run lengths
  int incl = wave_iscan(len, lane);
  if (lane == 63) wpart[wv] = incl;
  __syncthreads();
  int wpre = 0, tot = 0;
#pragma unroll
  for (int k = 0; k < 8; ++k) {
    int pv = wpart[k];
    if (k < wv) wpre += pv;
    tot += pv;
  }
  int pos = wpre + incl - len;  // exclusive prefix
  if (t < PA_NBLK) {
    rp[t] = pos;
    rs[t] = s;
  }
  if (t == 511) rp[PA_NBLK] = tot;
  __syncthreads();
  int ns = tot;
  if (ns > SLOT) ns = SLOT;  // statistically never
  // cooperative run copy: one 16-lane group per run (line-local reads)
  {
    int g = t >> 4, gl = t & 15;  // 32 groups
    for (int r = g; r < PA_NBLK; r += 32) {
      int P = rp[r];
      int L = rp[r + 1] - P;
      const unsigned* rw = colraw + (size_t)r * PA_EPB + rs[r];
      for (int j = gl; j < L; j += 16) {
        int p = P + j;
        if (p < SLOT) stage[p] = rw[j];
      }
    }
  }
  __syncthreads();
  // histogram over local_dst (512 bins)
  for (int i = t; i < ns; i += 512)
    atomicAdd(&hist[stage[i] >> 19], 1);
  __syncthreads();
  int deg = hist[t];               // in-degree of node h*512+t
  int incl2 = wave_iscan(deg, lane);
  if (lane == 63) wpart[wv] = incl2;
  __syncthreads();
  int wpre2 = 0;
#pragma unroll
  for (int k = 0; k < 8; ++k) {
    if (k < wv) wpre2 += wpart[k];
  }
  hist[t] = wpre2 + incl2 - deg;   // exclusive prefix
  __syncthreads();
  unsigned* base = col2 + (size_t)h * SLOT;
  for (int i = t; i < ns; i += 512) {
    unsigned p = stage[i];
    int posQ = atomicAdd(&hist[(int)(p >> 19)], 1);
    if (posQ < SLOT) base[swiz(posQ)] = p;
  }
  for (int j = ns + t; j < SLOT; j += 512) base[swiz(j)] = SENT;
  // node init: dis + folded layer-0 gather table
  int i = (h << BSH) + t;
  if (i < NN) {
    float d = rsqrtf((float)deg + 1.0f);
    dis[i] = d;
    float2 x = X[i];
    const float* sv = step_emb + step_index[0] * STEP_DIM;
    float c1_0 = 0.f, c1_1 = 0.f;
#pragma unroll
    for (int j = 0; j < STEP_DIM; ++j) {
      c1_0 += sv[j] * W0[20 + (2 + j) * 2 + 0];
      c1_1 += sv[j] * W0[20 + (2 + j) * 2 + 1];
    }
    qtab[i] = make_float2(d * (x.x * W0[20] + x.y * W0[22] + c1_0),
                          d * (x.x * W0[21] + x.y * W0[23] + c1_1));
  }
}

// ---- shared layer helpers --------------------------------------------------

// cached (non-NT) loads: col2 (40 MB) stays L3-resident across the 8 layers
__device__ __forceinline__ void load_ebuf(const unsigned* __restrict__ col2,
                                          int b, int w, int l, unsigned* ebuf) {
  const unsigned* bp = col2 + (size_t)b * SLOT + w * WSLOT + l * 4;
#pragma unroll
  for (int g = 0; g < 5; ++g) {
    u32x4 v = *(const u32x4*)(bp + g * 256);
    ebuf[g * 4 + 0] = v[0];
    ebuf[g * 4 + 1] = v[1];
    ebuf[g * 4 + 2] = v[2];
    ebuf[g * 4 + 3] = v[3];
  }
}

// All 20 gathers issued upfront, then the run-scan into LDS acc.
__device__ __forceinline__ void gather_acc(const unsigned* ebuf,
                                           const float2* __restrict__ tab,
                                           float* acc) {
  float2 vals[20];
#pragma unroll
  for (int j = 0; j < 20; ++j) vals[j] = tab[ebuf[j] & 0x7FFFF];
  int cur = BNOD;
  float rx = 0.f, ry = 0.f;
#pragma unroll
  for (int j = 0; j < 20; ++j) {
    int ld = (int)(ebuf[j] >> 19);
    if (ld != cur) {
      atomicAdd(&acc[cur * 2 + 0], rx);
      atomicAdd(&acc[cur * 2 + 1], ry);
      cur = ld;
      rx = vals[j].x;
      ry = vals[j].y;
    } else {
      rx += vals[j].x;
      ry += vals[j].y;
    }
  }
  atomicAdd(&acc[cur * 2 + 0], rx);
  atomicAdd(&acc[cur * 2 + 1], ry);
}

// ---- layer kernels ---------------------------------------------------------

__global__ __launch_bounds__(512, 4) void k_blayer0(const unsigned* __restrict__ col2,
                                                    const float2* __restrict__ qtab,
                                                    const float2* __restrict__ X,
                                                    const float* __restrict__ dis,
                                                    const float* __restrict__ W0,
                                                    const float* __restrict__ b0,
                                                    const float* __restrict__ step_emb,
                                                    const int* __restrict__ step_index,
                                                    float2* __restrict__ xs_out) {
  __shared__ float acc[(BNOD + 1) * 2];
  int b = blockIdx.x, t = threadIdx.x;
  for (int j = t; j < (BNOD + 1) * 2; j += 512) acc[j] = 0.f;
  __syncthreads();
  int w = t >> 6, l = t & 63;
  unsigned ebuf[20];
  load_ebuf(col2, b, w, l, ebuf);
  gather_acc(ebuf, qtab, acc);
  __syncthreads();
  const float* sv = step_emb + step_index[0] * STEP_DIM;
  float c00 = b0[0] + b0[2], c01 = b0[1] + b0[3];
#pragma unroll
  for (int j = 0; j < STEP_DIM; ++j) {
    c00 += sv[j] * W0[(2 + j) * 2 + 0];
    c01 += sv[j] * W0[(2 + j) * 2 + 1];
  }
  int i = (b << BSH) + t;
  if (i < NN) {
    float d = dis[i];
    float2 x = X[i];
    float2 qv = qtab[i];
    float h0 = c00 + x.x * W0[0] + x.y * W0[2] + d * (acc[t * 2 + 0] + qv.x);
    float h1 = c01 + x.x * W0[1] + x.y * W0[3] + d * (acc[t * 2 + 1] + qv.y);
    h0 = fmaxf(h0, 0.f);
    h1 = fmaxf(h1, 0.f);
    xs_out[i] = make_float2(d * h0, d * h1);
  }
}

__global__ __launch_bounds__(512, 4) void k_blayer(const unsigned* __restrict__ col2,
                                                   const float* __restrict__ dis,
                                                   const float2* __restrict__ xs_in,
                                                   const float* __restrict__ W,
                                                   const float* __restrict__ bb,
                                                   float2* __restrict__ xs_out,
                                                   float2* __restrict__ out,
                                                   int last) {
  __shared__ float acc[(BNOD + 1) * 2];
  int b = blockIdx.x, t = threadIdx.x;
  for (int j = t; j < (BNOD + 1) * 2; j += 512) acc[j] = 0.f;
  __syncthreads();
  int w = t >> 6, l = t & 63;
  unsigned ebuf[20];
  load_ebuf(col2, b, w, l, ebuf);
  gather_acc(ebuf, xs_in, acc);
  __syncthreads();
  int i = (b << BSH) + t;
  if (i < NN) {
    float d = dis[i];
    float2 xsv = xs_in[i];
    float inv = 1.0f / d;
    float xx = xsv.x * inv, xy = xsv.y * inv;
    float px = d * (acc[t * 2 + 0] + xsv.x);
    float py = d * (acc[t * 2 + 1] + xsv.y);
    float h0 = bb[0] + bb[2] + xx * W[0] + xy * W[2] + px * W[4] + py * W[6];
    float h1 = bb[1] + bb[3] + xx * W[1] + xy * W[3] + px * W[5] + py * W[7];
    h0 = fmaxf(h0, 0.f);
    h1 = fmaxf(h1, 0.f);
    if (last) {
      out[i] = make_float2(h0, h1);
    } else {
      xs_out[i] = make_float2(d * h0, d * h1);
    }
  }
}

// ---- driver ----------------------------------------------------------------

extern "C" void kernel_launch(void* const* d_in, const int* in_sizes, int n_in,
                              void* d_out, int out_size, void* d_ws, size_t ws_size,
                              hipStream_t stream) {
  const float2* X        = (const float2*)d_in[0];
  const int*    edge     = (const int*)d_in[1];
  const int*    src      = edge;
  const int*    dstp     = edge + NE;
  const int*    step_idx = (const int*)d_in[2];
  const float*  step_emb = (const float*)d_in[3];
  const float*  W0       = (const float*)d_in[4];
  const float*  b0       = (const float*)d_in[5];
  const float*  Wh       = (const float*)d_in[6];
  const float*  bbias    = (const float*)d_in[7];

  // ws ints: [col2: 977*10240][colraw: NE][starts2: 500*978 pad]
  //          [dis: 500224][bufA: 1000448][bufB: 1000448]
  int*      ip      = (int*)d_ws;
  unsigned* col2    = (unsigned*)ip;
  size_t    o       = (size_t)NBUK * SLOT;
  unsigned* colraw  = (unsigned*)(ip + o);  o += NE;
  int*      starts2 = ip + o;               o += ((size_t)PA_NBLK * PA_SC + 8) & ~(size_t)3;
  float*    dis     = (float*)(ip + o);     o += 500224;
  float2*   bufA    = (float2*)(ip + o);    o += 2 * 500224;
  float2*   bufB    = (float2*)(ip + o);

  k_lsort<<<PA_NBLK, 512, 0, stream>>>(src, dstp, colraw, starts2);
  k_sortA<<<NBUK, 512, 0, stream>>>(colraw, starts2, col2, X, W0,
                                    step_emb, step_idx, dis, bufA);

  k_blayer0<<<NBUK, 512, 0, stream>>>(col2, bufA, X, dis, W0, b0,
                                      step_emb, step_idx, bufB);
  float2* cur = bufB;
  float2* nxt = bufA;
  for (int l = 0; l < HIDM1; ++l) {
    k_blayer<<<NBUK, 512, 0, stream>>>(col2, dis, cur, Wh + l * 8,
                                       bbias + l * 4, nxt, (float2*)d_out,
                                       l == HIDM1 - 1 ? 1 : 0);
    float2* tmp = cur;
    cur = nxt;
    nxt = tmp;
  }
}